// Round 8
// baseline (1340.706 us; speedup 1.0000x reference)
//
#include <hip/hip_runtime.h>
#include <hip/hip_bf16.h>
#include <math.h>

// Problem constants
#define NN   1024
#define CS   384
#define CZ   128
#define HH   12
#define HCH  192
#define QPR  144
#define DCAT 2112
#define PROJW 1152    // 192+384+144+432
#define VO   480      // 12 h * (16 v + 24 vpt)
#define INF_ 100000.0f

#define SC_QK 0.14433756729740643f   // sqrt(1/48)
#define SC_B  0.5773502691896258f    // sqrt(1/3)
#define SC_PT 0.13608276348795434f   // sqrt(1/54)

__device__ __forceinline__ float dot4(float4 a, float4 b) {
  return a.x * b.x + a.y * b.y + a.z * b.z + a.w * b.w;
}

// ---------------------------------------------------------------------------
// proj_all: fused s @ {wq,wkv,wqp,wkvp} + bias -> proj[n][1152]
// ---------------------------------------------------------------------------
__global__ __launch_bounds__(256) void proj_all(
    const float* __restrict__ s,
    const float* __restrict__ wq, const float* __restrict__ bq,
    const float* __restrict__ wkv, const float* __restrict__ bkv,
    const float* __restrict__ wqp, const float* __restrict__ bqp,
    const float* __restrict__ wkvp, const float* __restrict__ bkvp,
    float* __restrict__ proj)
{
  __shared__ float s_lds[8 * CS];
  const int n0 = blockIdx.x * 8;
  for (int idx = threadIdx.x; idx < 8 * CS; idx += 256)
    s_lds[idx] = s[(size_t)(n0 + idx / CS) * CS + (idx % CS)];
  __syncthreads();

  const int gc = blockIdx.y * 128 + (threadIdx.x & 31) * 4;
  const int rg = threadIdx.x >> 5;
  const float* wp; const float* bp; int OUT, lc;
  if (gc < 192)      { wp = wq;   bp = bq;   OUT = 192; lc = gc; }
  else if (gc < 576) { wp = wkv;  bp = bkv;  OUT = 384; lc = gc - 192; }
  else if (gc < 720) { wp = wqp;  bp = bqp;  OUT = 144; lc = gc - 576; }
  else               { wp = wkvp; bp = bkvp; OUT = 432; lc = gc - 720; }

  float a0 = 0.f, a1 = 0.f, a2 = 0.f, a3 = 0.f;
  const float* srow = &s_lds[rg * CS];
#pragma unroll 4
  for (int kk = 0; kk < CS; kk++) {
    float sv = srow[kk];
    float4 w4 = *reinterpret_cast<const float4*>(&wp[(size_t)kk * OUT + lc]);
    a0 += sv * w4.x; a1 += sv * w4.y; a2 += sv * w4.z; a3 += sv * w4.w;
  }
  float* o = proj + (size_t)(n0 + rg) * PROJW + gc;
  o[0] = a0 + bp[lc]; o[1] = a1 + bp[lc + 1];
  o[2] = a2 + bp[lc + 2]; o[3] = a3 + bp[lc + 3];
}

// ---------------------------------------------------------------------------
// transform: split kv, rotate/translate points. Writes:
//   kc[(h*16+c)*NN+n], kpc[(h*12+d)*NN+n], knc[h*NN+n]  (component-major)
//   vo[n*480 + h*40 + c]  (interleaved: c<16 = v, 16..39 = v_pts comps)
//   q_pts[n][144], qn[n][12]
// ---------------------------------------------------------------------------
__global__ __launch_bounds__(256) void ipa_transform(
    const float* __restrict__ proj, const float* __restrict__ rot,
    const float* __restrict__ trans,
    float* __restrict__ kc, float* __restrict__ kpc, float* __restrict__ knc,
    float* __restrict__ vo, float* __restrict__ q_pts, float* __restrict__ qn)
{
  const int n = blockIdx.x, tid = threadIdx.x;
  const float* pr = proj + (size_t)n * PROJW;
  __shared__ float R[9], T[3], sq_q[48], sq_k[48];
  if (tid < 9) R[tid] = rot[n * 9 + tid];
  if (tid < 3) T[tid] = trans[n * 3 + tid];
  __syncthreads();
  if (tid < HCH) {
    int h = tid >> 4, c = tid & 15;
    kc[(size_t)(h * 16 + c) * NN + n] = pr[192 + h * 32 + c];
    vo[(size_t)n * VO + h * 40 + c]   = pr[192 + h * 32 + 16 + c];
  }
  if (tid < 48) {
    float r0 = pr[576 + tid], r1 = pr[576 + 48 + tid], r2 = pr[576 + 96 + tid];
    float x = R[0] * r0 + R[1] * r1 + R[2] * r2 + T[0];
    float y = R[3] * r0 + R[4] * r1 + R[5] * r2 + T[1];
    float z = R[6] * r0 + R[7] * r1 + R[8] * r2 + T[2];
    q_pts[(size_t)n * QPR + tid * 3 + 0] = x;
    q_pts[(size_t)n * QPR + tid * 3 + 1] = y;
    q_pts[(size_t)n * QPR + tid * 3 + 2] = z;
    sq_q[tid] = x * x + y * y + z * z;
  }
  if (tid >= 64 && tid < 208) {
    int t = tid - 64;
    float r0 = pr[720 + t], r1 = pr[720 + 144 + t], r2 = pr[720 + 288 + t];
    float x = R[0] * r0 + R[1] * r1 + R[2] * r2 + T[0];
    float y = R[3] * r0 + R[4] * r1 + R[5] * r2 + T[1];
    float z = R[6] * r0 + R[7] * r1 + R[8] * r2 + T[2];
    int h = t / 12, pp = t % 12;
    if (pp < 4) {
      int d = pp * 3;
      kpc[(size_t)(h * 12 + d + 0) * NN + n] = x;
      kpc[(size_t)(h * 12 + d + 1) * NN + n] = y;
      kpc[(size_t)(h * 12 + d + 2) * NN + n] = z;
      sq_k[h * 4 + pp] = x * x + y * y + z * z;
    } else {
      int d = (pp - 4) * 3;
      float* vb = vo + (size_t)n * VO + h * 40 + 16 + d;
      vb[0] = x; vb[1] = y; vb[2] = z;
    }
  }
  __syncthreads();
  if (tid < HH) {
    float a = 0.f, b = 0.f;
#pragma unroll
    for (int p = 0; p < 4; p++) { a += sq_q[tid * 4 + p]; b += sq_k[tid * 4 + p]; }
    qn[n * HH + tid] = a;
    knc[(size_t)tid * NN + n] = b;
  }
}

// ---------------------------------------------------------------------------
// logit_pre: L0[i,j,h] = SC_QK*qk + SC_B*bb[h] - 0.5hw*(qn+kn-2cr)
//            + INF*(mi*mj-1)   (fp32, everything except the z-bias term).
// grid (NN/4, HH), block 256: warp = (i,h), lane = 4 consecutive j.
// ---------------------------------------------------------------------------
__global__ __launch_bounds__(256) void logit_pre(
    const float* __restrict__ kc, const float* __restrict__ kpc,
    const float* __restrict__ knc, const float* __restrict__ proj,
    const float* __restrict__ q_pts, const float* __restrict__ qn,
    const float* __restrict__ bb, const float* __restrict__ head_w,
    const float* __restrict__ mask, float* __restrict__ L0f)
{
  const int h = blockIdx.y;
  const int i = blockIdx.x * 4 + (threadIdx.x >> 6);
  const int lane = threadIdx.x & 63;

  const float* qb = proj + (size_t)i * PROJW + h * 16;
  const float4 q0 = *reinterpret_cast<const float4*>(qb);
  const float4 q1 = *reinterpret_cast<const float4*>(qb + 4);
  const float4 q2 = *reinterpret_cast<const float4*>(qb + 8);
  const float4 q3 = *reinterpret_cast<const float4*>(qb + 12);
  const float* pb = q_pts + (size_t)i * QPR + h * 12;
  const float4 p0 = *reinterpret_cast<const float4*>(pb);
  const float4 p1 = *reinterpret_cast<const float4*>(pb + 4);
  const float4 p2 = *reinterpret_cast<const float4*>(pb + 8);
  const float qnv = qn[i * HH + h];
  const float xw = head_w[h];
  const float hwv = ((xw > 20.f) ? xw : log1pf(__expf(xw))) * SC_PT;
  const float base = SC_B * bb[h];
  const float mi = mask[i];

  const float* kch  = kc  + (size_t)h * 16 * NN;
  const float* kpch = kpc + (size_t)h * 12 * NN;
  const float* knch = knc + (size_t)h * NN;

#pragma unroll
  for (int t = 0; t < 4; t++) {
    const int j = t * 256 + lane * 4;
    float4 d = {0, 0, 0, 0};
#pragma unroll
    for (int c = 0; c < 16; c++) {
      const float qc = (c < 4 ? (&q0.x)[c] : c < 8 ? (&q1.x)[c - 4]
                       : c < 12 ? (&q2.x)[c - 8] : (&q3.x)[c - 12]);
      float4 kv = *reinterpret_cast<const float4*>(&kch[(size_t)c * NN + j]);
      d.x += qc * kv.x; d.y += qc * kv.y; d.z += qc * kv.z; d.w += qc * kv.w;
    }
    float4 cr = {0, 0, 0, 0};
#pragma unroll
    for (int dd = 0; dd < 12; dd++) {
      const float pc = (dd < 4 ? (&p0.x)[dd] : dd < 8 ? (&p1.x)[dd - 4]
                        : (&p2.x)[dd - 8]);
      float4 kv = *reinterpret_cast<const float4*>(&kpch[(size_t)dd * NN + j]);
      cr.x += pc * kv.x; cr.y += pc * kv.y; cr.z += pc * kv.z; cr.w += pc * kv.w;
    }
    float4 kn4 = *reinterpret_cast<const float4*>(&knch[j]);
    float4 m4 = *reinterpret_cast<const float4*>(&mask[j]);
    float L[4];
    L[0] = SC_QK * d.x + base - 0.5f * hwv * (qnv + kn4.x - 2.f * cr.x)
           + INF_ * (mi * m4.x - 1.f);
    L[1] = SC_QK * d.y + base - 0.5f * hwv * (qnv + kn4.y - 2.f * cr.y)
           + INF_ * (mi * m4.y - 1.f);
    L[2] = SC_QK * d.z + base - 0.5f * hwv * (qnv + kn4.z - 2.f * cr.z)
           + INF_ * (mi * m4.z - 1.f);
    L[3] = SC_QK * d.w + base - 0.5f * hwv * (qnv + kn4.w - 2.f * cr.w)
           + INF_ * (mi * m4.w - 1.f);
#pragma unroll
    for (int u = 0; u < 4; u++)
      L0f[((size_t)i * NN + j + u) * HH + h] = L[u];
  }
}

// ---------------------------------------------------------------------------
// ipa_flash2: ONE z pass for bias + online softmax + o_pair + o + o_pt.
// One block per i (256 threads). Per 64-j tile:
//   A: bias dot (direct-global z float4, csub-split) + L0 -> logits in pl
//   B: online softmax (4 warps x 3 heads), rescale factor f
//   C: o_pair accumulate (z re-read from L2, coalesced float2)
//   D: o/o_pt accumulate from interleaved vo[j][480]
// LDS ~10 KB, low VGPR -> 4+ blocks/CU so barriers overlap across blocks.
// ---------------------------------------------------------------------------
__global__ __launch_bounds__(256) void ipa_flash2(
    const float* __restrict__ z, const float* __restrict__ wb,
    const float* __restrict__ L0f, const float* __restrict__ vo,
    float* __restrict__ cat, float* __restrict__ optb)
{
  __shared__ float wb_s[HH * CZ];     // [h][c], 6 KB
  __shared__ float pl[HH * 68];       // logits -> probs, 3.2 KB
  __shared__ float m_s[HH], l_s[HH], f_s[HH];

  const int i = blockIdx.x, tid = threadIdx.x;
  const int jl = tid >> 2, csub = tid & 3;       // phase A
  const int hq = tid >> 6, c2 = tid & 63;        // phase C
  const int r1 = tid,       h1 = r1 / 40, d1 = r1 - h1 * 40;   // phase D
  const int r2 = tid + 256, h2 = r2 / 40, d2 = r2 - h2 * 40;
  const bool has2 = (r2 < VO);

  for (int e = tid; e < HH * CZ; e += 256) {
    int c = e / HH, h = e - c * HH;              // coalesced read of wb[c][h]
    wb_s[h * CZ + c] = wb[e];
  }
  if (tid < HH) { m_s[tid] = -1e30f; l_s[tid] = 0.f; }
  __syncthreads();

  float aop[3][2];
#pragma unroll
  for (int u = 0; u < 3; u++) { aop[u][0] = 0.f; aop[u][1] = 0.f; }
  float av1 = 0.f, av2 = 0.f;

  for (int tt = 0; tt < 16; tt++) {
    const int jb = tt * 64;
    // ---- Phase A: logits ----
    {
      float bd[HH];
#pragma unroll
      for (int h = 0; h < HH; h++) bd[h] = 0.f;
      const float* zb = z + ((size_t)i * NN + jb + jl) * CZ + csub * 4;
#pragma unroll
      for (int k8 = 0; k8 < 8; k8++) {
        float4 zq = *reinterpret_cast<const float4*>(&zb[k8 * 16]);
        const int c = csub * 4 + k8 * 16;
#pragma unroll
        for (int h = 0; h < HH; h++)
          bd[h] += dot4(zq, *reinterpret_cast<const float4*>(&wb_s[h * CZ + c]));
      }
#pragma unroll
      for (int h = 0; h < HH; h++) {
        bd[h] += __shfl_xor(bd[h], 1);
        bd[h] += __shfl_xor(bd[h], 2);
      }
      if (csub == 0) {
        const float* l0 = &L0f[((size_t)i * NN + jb + jl) * HH];
        float4 La = *reinterpret_cast<const float4*>(&l0[0]);
        float4 Lb = *reinterpret_cast<const float4*>(&l0[4]);
        float4 Lc = *reinterpret_cast<const float4*>(&l0[8]);
        pl[0 * 68 + jl]  = La.x + SC_B * bd[0];
        pl[1 * 68 + jl]  = La.y + SC_B * bd[1];
        pl[2 * 68 + jl]  = La.z + SC_B * bd[2];
        pl[3 * 68 + jl]  = La.w + SC_B * bd[3];
        pl[4 * 68 + jl]  = Lb.x + SC_B * bd[4];
        pl[5 * 68 + jl]  = Lb.y + SC_B * bd[5];
        pl[6 * 68 + jl]  = Lb.z + SC_B * bd[6];
        pl[7 * 68 + jl]  = Lb.w + SC_B * bd[7];
        pl[8 * 68 + jl]  = Lc.x + SC_B * bd[8];
        pl[9 * 68 + jl]  = Lc.y + SC_B * bd[9];
        pl[10 * 68 + jl] = Lc.z + SC_B * bd[10];
        pl[11 * 68 + jl] = Lc.w + SC_B * bd[11];
      }
    }
    __syncthreads();
    // ---- Phase B: online softmax ----
    {
      const int w = tid >> 6, lane = tid & 63;
#pragma unroll
      for (int u = 0; u < 3; u++) {
        const int h = w * 3 + u;
        float lv = pl[h * 68 + lane];
        float tmax = lv;
        for (int off = 32; off; off >>= 1)
          tmax = fmaxf(tmax, __shfl_xor(tmax, off));
        float m_old = m_s[h];
        float m_new = fmaxf(m_old, tmax);
        float p = __expf(lv - m_new);
        pl[h * 68 + lane] = p;
        float psum = p;
        for (int off = 32; off; off >>= 1) psum += __shfl_xor(psum, off);
        if (lane == 0) {
          float f = __expf(m_old - m_new);
          l_s[h] = l_s[h] * f + psum;
          m_s[h] = m_new;
          f_s[h] = f;
        }
      }
    }
    __syncthreads();
    // ---- Phase C: o_pair accumulate (z re-read, L2-hot) ----
    {
      const float f0 = f_s[hq * 3 + 0];
      const float f1 = f_s[hq * 3 + 1];
      const float f2 = f_s[hq * 3 + 2];
      aop[0][0] *= f0; aop[0][1] *= f0;
      aop[1][0] *= f1; aop[1][1] *= f1;
      aop[2][0] *= f2; aop[2][1] *= f2;
      const float* zc = z + ((size_t)i * NN + jb) * CZ + c2 * 2;
      const float* ph0 = &pl[(hq * 3 + 0) * 68];
      const float* ph1 = &pl[(hq * 3 + 1) * 68];
      const float* ph2 = &pl[(hq * 3 + 2) * 68];
#pragma unroll 4
      for (int j = 0; j < 64; j++) {
        float2 zq = *reinterpret_cast<const float2*>(&zc[(size_t)j * CZ]);
        float p0 = ph0[j], p1 = ph1[j], p2 = ph2[j];
        aop[0][0] += p0 * zq.x; aop[0][1] += p0 * zq.y;
        aop[1][0] += p1 * zq.x; aop[1][1] += p1 * zq.y;
        aop[2][0] += p2 * zq.x; aop[2][1] += p2 * zq.y;
      }
    }
    // ---- Phase D: o / o_pt accumulate ----
    {
      av1 *= f_s[h1];
      if (has2) av2 *= f_s[h2];
      const float* vb = vo + (size_t)jb * VO;
      const float* ph1p = &pl[h1 * 68];
      const float* ph2p = &pl[h2 * 68];
#pragma unroll 4
      for (int j = 0; j < 64; j++) {
        const float* vr = &vb[(size_t)j * VO];
        av1 += ph1p[j] * vr[r1];
        if (has2) av2 += ph2p[j] * vr[r2];
      }
    }
    __syncthreads();
  }
  // ---- Epilogue ----
  {
    float* catr = cat + (size_t)i * DCAT;
    const float il0 = 1.f / l_s[hq * 3 + 0];
    const float il1 = 1.f / l_s[hq * 3 + 1];
    const float il2 = 1.f / l_s[hq * 3 + 2];
    catr[576 + (hq * 3 + 0) * CZ + c2 * 2 + 0] = aop[0][0] * il0;
    catr[576 + (hq * 3 + 0) * CZ + c2 * 2 + 1] = aop[0][1] * il0;
    catr[576 + (hq * 3 + 1) * CZ + c2 * 2 + 0] = aop[1][0] * il1;
    catr[576 + (hq * 3 + 1) * CZ + c2 * 2 + 1] = aop[1][1] * il1;
    catr[576 + (hq * 3 + 2) * CZ + c2 * 2 + 0] = aop[2][0] * il2;
    catr[576 + (hq * 3 + 2) * CZ + c2 * 2 + 1] = aop[2][1] * il2;
    float v1 = av1 / l_s[h1];
    if (d1 < 16) catr[h1 * 16 + d1] = v1;
    else optb[((size_t)i * HH + h1) * 24 + (d1 - 16)] = v1;
    if (has2) {
      float v2 = av2 / l_s[h2];
      if (d2 < 16) catr[h2 * 16 + d2] = v2;
      else optb[((size_t)i * HH + h2) * 24 + (d2 - 16)] = v2;
    }
  }
}

// ---------------------------------------------------------------------------
// ipa_finish: inverse-rotate o_pt, norms -> cat[192:576]. grid NN, block 128.
// ---------------------------------------------------------------------------
__global__ __launch_bounds__(128) void ipa_finish(
    const float* __restrict__ optb, const float* __restrict__ rot,
    const float* __restrict__ trans, float* __restrict__ cat)
{
  const int i = blockIdx.x, tid = threadIdx.x;
  __shared__ float R_s[9], T_s[3];
  if (tid < 9) R_s[tid] = rot[i * 9 + tid];
  if (tid < 3) T_s[tid] = trans[i * 3 + tid];
  __syncthreads();
  if (tid < 96) {
    int h = tid >> 3, p = tid & 7;
    const float* ob = optb + ((size_t)i * HH + h) * 24 + p * 3;
    float gx = ob[0] - T_s[0];
    float gy = ob[1] - T_s[1];
    float gz = ob[2] - T_s[2];
    float lx = R_s[0] * gx + R_s[3] * gy + R_s[6] * gz;
    float ly = R_s[1] * gx + R_s[4] * gy + R_s[7] * gz;
    float lz = R_s[2] * gx + R_s[5] * gy + R_s[8] * gz;
    float* catr = cat + (size_t)i * DCAT;
    catr[192 + 0 * 96 + h * 8 + p] = lx;
    catr[192 + 1 * 96 + h * 8 + p] = ly;
    catr[192 + 2 * 96 + h * 8 + p] = lz;
    catr[480 + h * 8 + p] = sqrtf(lx * lx + ly * ly + lz * lz + 1e-8f);
  }
}

// ---------------------------------------------------------------------------
// out_gemm: out = cat @ wout + bout  (1024 x 2112 x 384)
// ---------------------------------------------------------------------------
__global__ __launch_bounds__(256) void out_gemm(
    const float* __restrict__ cat, const float* __restrict__ wout,
    const float* __restrict__ bout, float* __restrict__ out)
{
  __shared__ float c_lds[4 * DCAT];
  const int n0 = blockIdx.x * 4;
  const int cq = blockIdx.y * 128 + (threadIdx.x & 63) * 2;
  const int rg = threadIdx.x >> 6;
  for (int idx = threadIdx.x; idx < 4 * DCAT; idx += 256) {
    int r = idx / DCAT, kk = idx - r * DCAT;
    c_lds[idx] = cat[(size_t)(n0 + r) * DCAT + kk];
  }
  __syncthreads();
  float a0 = 0.f, a1 = 0.f;
  const float* crow = &c_lds[rg * DCAT];
#pragma unroll 4
  for (int kk = 0; kk < DCAT; kk++) {
    float cv = crow[kk];
    float2 w2 = *reinterpret_cast<const float2*>(&wout[(size_t)kk * CS + cq]);
    a0 += cv * w2.x; a1 += cv * w2.y;
  }
  float* o = out + (size_t)(n0 + rg) * CS + cq;
  o[0] = a0 + bout[cq]; o[1] = a1 + bout[cq + 1];
}

// ---------------------------------------------------------------------------
extern "C" void kernel_launch(void* const* d_in, const int* in_sizes, int n_in,
                              void* d_out, int out_size, void* d_ws, size_t ws_size,
                              hipStream_t stream) {
  const float* s      = (const float*)d_in[0];
  const float* z      = (const float*)d_in[1];
  const float* rot    = (const float*)d_in[2];
  const float* trans  = (const float*)d_in[3];
  const float* mask   = (const float*)d_in[4];
  const float* wq     = (const float*)d_in[5];
  const float* bq     = (const float*)d_in[6];
  const float* wkv    = (const float*)d_in[7];
  const float* bkv    = (const float*)d_in[8];
  const float* wqp    = (const float*)d_in[9];
  const float* bqp    = (const float*)d_in[10];
  const float* wkvp   = (const float*)d_in[11];
  const float* bkvp   = (const float*)d_in[12];
  const float* wb     = (const float*)d_in[13];
  const float* bb     = (const float*)d_in[14];
  const float* head_w = (const float*)d_in[15];
  const float* wout   = (const float*)d_in[16];
  const float* bout   = (const float*)d_in[17];
  float* out = (float*)d_out;

  // workspace layout (floats; all bases 16-float aligned)
  float* ws = (float*)d_ws;
  float* proj_buf = ws;                                  // 1,179,648
  float* kc_buf   = proj_buf + (size_t)NN * PROJW;       // 196,608
  float* kpc_buf  = kc_buf + (size_t)HH * 16 * NN;       // 147,456
  float* knc_buf  = kpc_buf + (size_t)HH * 12 * NN;      // 12,288
  float* qpts_buf = knc_buf + (size_t)HH * NN;           // 147,456
  float* qn_buf   = qpts_buf + (size_t)NN * QPR;         // 12,288
  float* vo_buf   = qn_buf + NN * HH;                    // 491,520
  float* optb_buf = vo_buf + (size_t)NN * VO;            // 294,912
  float* cat_buf  = optb_buf + (size_t)NN * HH * 24;     // 2,162,688
  float* L0f_buf  = cat_buf + (size_t)NN * DCAT;         // 12,582,912

  proj_all<<<dim3(NN / 8, 9), dim3(256), 0, stream>>>(
      s, wq, bq, wkv, bkv, wqp, bqp, wkvp, bkvp, proj_buf);
  ipa_transform<<<dim3(NN), dim3(256), 0, stream>>>(
      proj_buf, rot, trans, kc_buf, kpc_buf, knc_buf, vo_buf,
      qpts_buf, qn_buf);
  logit_pre<<<dim3(NN / 4, HH), dim3(256), 0, stream>>>(
      kc_buf, kpc_buf, knc_buf, proj_buf, qpts_buf, qn_buf,
      bb, head_w, mask, L0f_buf);
  ipa_flash2<<<dim3(NN), dim3(256), 0, stream>>>(
      z, wb, L0f_buf, vo_buf, cat_buf, optb_buf);
  ipa_finish<<<dim3(NN), dim3(128), 0, stream>>>(optb_buf, rot, trans, cat_buf);
  out_gemm<<<dim3(NN / 4, 3), dim3(256), 0, stream>>>(
      cat_buf, wout, bout, out);
}

// Round 9
// 730.996 us; speedup vs baseline: 1.8341x; 1.8341x over previous
//
#include <hip/hip_runtime.h>
#include <hip/hip_bf16.h>
#include <math.h>

// Problem constants
#define NN   1024
#define CS   384
#define CZ   128
#define HH   12
#define HCH  192
#define QPR  144
#define DCAT 2112
#define PROJW 1152    // 192+384+144+432
#define INF_ 100000.0f

#define SC_QK 0.14433756729740643f   // sqrt(1/48)
#define SC_B  0.5773502691896258f    // sqrt(1/3)
#define SC_PT 0.13608276348795434f   // sqrt(1/54)

__device__ __forceinline__ float dot4(float4 a, float4 b) {
  return a.x * b.x + a.y * b.y + a.z * b.z + a.w * b.w;
}
__device__ __forceinline__ float bf2f(unsigned short u) {
  unsigned int v = ((unsigned int)u) << 16;
  float f; __builtin_memcpy(&f, &v, 4); return f;
}
__device__ __forceinline__ unsigned short f2bf(float f) {
  __hip_bfloat16 h = __float2bfloat16(f);
  unsigned short u; __builtin_memcpy(&u, &h, 2); return u;
}

// ---------------------------------------------------------------------------
// prep: wb_t[h][c] transpose + softplus(head_w) scale
// ---------------------------------------------------------------------------
__global__ void prep(const float* __restrict__ wb, const float* __restrict__ head_w,
                     float* __restrict__ wb_t, float* __restrict__ hw)
{
  int t = threadIdx.x;
  for (int idx = t; idx < CZ * HH; idx += 256) {
    int c = idx % HH == idx % HH ? idx / HH : 0;  // c = idx/12
    int h = idx - c * HH;
    wb_t[h * CZ + c] = wb[idx];
  }
  if (t < HH) {
    float x = head_w[t];
    float sp = (x > 20.f) ? x : log1pf(__expf(x));
    hw[t] = sp * SC_PT;
  }
}

// ---------------------------------------------------------------------------
// proj_all: fused s @ {wq,wkv,wqp,wkvp} + bias -> proj[n][1152]
// ---------------------------------------------------------------------------
__global__ __launch_bounds__(256) void proj_all(
    const float* __restrict__ s,
    const float* __restrict__ wq, const float* __restrict__ bq,
    const float* __restrict__ wkv, const float* __restrict__ bkv,
    const float* __restrict__ wqp, const float* __restrict__ bqp,
    const float* __restrict__ wkvp, const float* __restrict__ bkvp,
    float* __restrict__ proj)
{
  __shared__ float s_lds[8 * CS];
  const int n0 = blockIdx.x * 8;
  for (int idx = threadIdx.x; idx < 8 * CS; idx += 256)
    s_lds[idx] = s[(size_t)(n0 + idx / CS) * CS + (idx % CS)];
  __syncthreads();

  const int gc = blockIdx.y * 128 + (threadIdx.x & 31) * 4;
  const int rg = threadIdx.x >> 5;
  const float* wp; const float* bp; int OUT, lc;
  if (gc < 192)      { wp = wq;   bp = bq;   OUT = 192; lc = gc; }
  else if (gc < 576) { wp = wkv;  bp = bkv;  OUT = 384; lc = gc - 192; }
  else if (gc < 720) { wp = wqp;  bp = bqp;  OUT = 144; lc = gc - 576; }
  else               { wp = wkvp; bp = bkvp; OUT = 432; lc = gc - 720; }

  float a0 = 0.f, a1 = 0.f, a2 = 0.f, a3 = 0.f;
  const float* srow = &s_lds[rg * CS];
#pragma unroll 4
  for (int kk = 0; kk < CS; kk++) {
    float sv = srow[kk];
    float4 w4 = *reinterpret_cast<const float4*>(&wp[(size_t)kk * OUT + lc]);
    a0 += sv * w4.x; a1 += sv * w4.y; a2 += sv * w4.z; a3 += sv * w4.w;
  }
  float* o = proj + (size_t)(n0 + rg) * PROJW + gc;
  o[0] = a0 + bp[lc]; o[1] = a1 + bp[lc + 1];
  o[2] = a2 + bp[lc + 2]; o[3] = a3 + bp[lc + 3];
}

// ---------------------------------------------------------------------------
// transform: split kv, rotate/translate points, write COMPONENT-MAJOR layouts
// ---------------------------------------------------------------------------
__global__ __launch_bounds__(256) void ipa_transform(
    const float* __restrict__ proj, const float* __restrict__ rot,
    const float* __restrict__ trans,
    float* __restrict__ kc, float* __restrict__ vc,
    float* __restrict__ q_pts, float* __restrict__ kpc,
    float* __restrict__ vpc, float* __restrict__ qn, float* __restrict__ knc)
{
  const int n = blockIdx.x, tid = threadIdx.x;
  const float* pr = proj + (size_t)n * PROJW;
  __shared__ float R[9], T[3], sq_q[48], sq_k[48];
  if (tid < 9) R[tid] = rot[n * 9 + tid];
  if (tid < 3) T[tid] = trans[n * 3 + tid];
  __syncthreads();
  if (tid < HCH) {
    int h = tid >> 4, c = tid & 15;
    kc[(size_t)(h * 16 + c) * NN + n] = pr[192 + h * 32 + c];
    vc[(size_t)(h * 16 + c) * NN + n] = pr[192 + h * 32 + 16 + c];
  }
  if (tid < 48) {
    float r0 = pr[576 + tid], r1 = pr[576 + 48 + tid], r2 = pr[576 + 96 + tid];
    float x = R[0] * r0 + R[1] * r1 + R[2] * r2 + T[0];
    float y = R[3] * r0 + R[4] * r1 + R[5] * r2 + T[1];
    float z = R[6] * r0 + R[7] * r1 + R[8] * r2 + T[2];
    q_pts[(size_t)n * QPR + tid * 3 + 0] = x;
    q_pts[(size_t)n * QPR + tid * 3 + 1] = y;
    q_pts[(size_t)n * QPR + tid * 3 + 2] = z;
    sq_q[tid] = x * x + y * y + z * z;
  }
  if (tid >= 64 && tid < 208) {
    int t = tid - 64;
    float r0 = pr[720 + t], r1 = pr[720 + 144 + t], r2 = pr[720 + 288 + t];
    float x = R[0] * r0 + R[1] * r1 + R[2] * r2 + T[0];
    float y = R[3] * r0 + R[4] * r1 + R[5] * r2 + T[1];
    float z = R[6] * r0 + R[7] * r1 + R[8] * r2 + T[2];
    int h = t / 12, pp = t % 12;
    if (pp < 4) {
      int d = pp * 3;
      kpc[(size_t)(h * 12 + d + 0) * NN + n] = x;
      kpc[(size_t)(h * 12 + d + 1) * NN + n] = y;
      kpc[(size_t)(h * 12 + d + 2) * NN + n] = z;
      sq_k[h * 4 + pp] = x * x + y * y + z * z;
    } else {
      int d = (pp - 4) * 3;
      vpc[(size_t)(h * 24 + d + 0) * NN + n] = x;
      vpc[(size_t)(h * 24 + d + 1) * NN + n] = y;
      vpc[(size_t)(h * 24 + d + 2) * NN + n] = z;
    }
  }
  __syncthreads();
  if (tid < HH) {
    float a = 0.f, b = 0.f;
#pragma unroll
    for (int p = 0; p < 4; p++) { a += sq_q[tid * 4 + p]; b += sq_k[tid * 4 + p]; }
    qn[n * HH + tid] = a;
    knc[(size_t)tid * NN + n] = b;
  }
}

// ---------------------------------------------------------------------------
// bias_pass v4: B[i,h,j] = sum_c z[i,j,c]*wb_t[h,c] (bf16 out).
// grid (8, 1024), block 256; thread (jl=tid>>2, csub=tid&3) owns 2 rows.
// All 16 z float4 loads are issued into registers BEFORE any FMA (max MLP).
// ---------------------------------------------------------------------------
__global__ __launch_bounds__(256) void bias_pass(
    const float* __restrict__ z, const float* __restrict__ wb_t,
    __hip_bfloat16* __restrict__ B)
{
  __shared__ float wb_s[HH * CZ];      // [h][c], 6 KB
  __shared__ float bias_s[HH * 128];   // 6 KB
  const int i = blockIdx.y;
  const int jb = blockIdx.x * 128;
  const int tid = threadIdx.x;
  const int jl = tid >> 2, csub = tid & 3;

  for (int e = tid; e < HH * CZ; e += 256) wb_s[e] = wb_t[e];
  __syncthreads();

  const float* zb = z + ((size_t)i * NN + jb + jl) * CZ + csub * 4;
  float4 zq0[8], zq1[8];
#pragma unroll
  for (int k8 = 0; k8 < 8; k8++)
    zq0[k8] = *reinterpret_cast<const float4*>(&zb[k8 * 16]);
#pragma unroll
  for (int k8 = 0; k8 < 8; k8++)
    zq1[k8] = *reinterpret_cast<const float4*>(&zb[(size_t)64 * CZ + k8 * 16]);

  float bd0[HH], bd1[HH];
#pragma unroll
  for (int h = 0; h < HH; h++) { bd0[h] = 0.f; bd1[h] = 0.f; }

#pragma unroll
  for (int k8 = 0; k8 < 8; k8++) {
    const int c = csub * 4 + k8 * 16;
#pragma unroll
    for (int h = 0; h < HH; h++) {
      float4 wv = *reinterpret_cast<const float4*>(&wb_s[h * CZ + c]);
      bd0[h] += dot4(zq0[k8], wv);
      bd1[h] += dot4(zq1[k8], wv);
    }
  }
#pragma unroll
  for (int h = 0; h < HH; h++) {
    bd0[h] += __shfl_xor(bd0[h], 1); bd0[h] += __shfl_xor(bd0[h], 2);
    bd1[h] += __shfl_xor(bd1[h], 1); bd1[h] += __shfl_xor(bd1[h], 2);
  }
  if (csub == 0) {
#pragma unroll
    for (int h = 0; h < HH; h++) {
      bias_s[h * 128 + jl] = bd0[h];
      bias_s[h * 128 + 64 + jl] = bd1[h];
    }
  }
  __syncthreads();
  for (int e = tid; e < HH * 128; e += 256) {
    int h = e >> 7, j2 = e & 127;
    B[((size_t)i * HH + h) * NN + jb + j2] = __float2bfloat16(bias_s[e]);
  }
}

// ---------------------------------------------------------------------------
// ipa_attn (v2, known-good): one WARP per (i, h). grid (NN/4, HH), block 256.
// ---------------------------------------------------------------------------
__global__ __launch_bounds__(256) void ipa_attn(
    const float* __restrict__ kc, const float* __restrict__ kpc,
    const float* __restrict__ knc, const float* __restrict__ vc,
    const float* __restrict__ vpc, const float* __restrict__ proj,
    const float* __restrict__ q_pts, const float* __restrict__ qn,
    const float* __restrict__ bb, const float* __restrict__ hw,
    const float* __restrict__ mask,
    __hip_bfloat16* __restrict__ A, float* __restrict__ cat,
    float* __restrict__ optb)
{
  const int h = blockIdx.y;
  const int i = blockIdx.x * 4 + (threadIdx.x >> 6);
  const int lane = threadIdx.x & 63;

  const float* qb = proj + (size_t)i * PROJW + h * 16;
  const float4 q0 = *reinterpret_cast<const float4*>(qb);
  const float4 q1 = *reinterpret_cast<const float4*>(qb + 4);
  const float4 q2 = *reinterpret_cast<const float4*>(qb + 8);
  const float4 q3 = *reinterpret_cast<const float4*>(qb + 12);
  const float* pb = q_pts + (size_t)i * QPR + h * 12;
  const float4 p0 = *reinterpret_cast<const float4*>(pb);
  const float4 p1 = *reinterpret_cast<const float4*>(pb + 4);
  const float4 p2 = *reinterpret_cast<const float4*>(pb + 8);
  const float qnv = qn[i * HH + h];
  const float bbv = bb[h];
  const float hwv = hw[h];
  const float mi = mask[i];

  const float* kch  = kc  + (size_t)h * 16 * NN;
  const float* kpch = kpc + (size_t)h * 12 * NN;
  const float* knch = knc + (size_t)h * NN;
  const float* vch  = vc  + (size_t)h * 16 * NN;
  const float* vpch = vpc + (size_t)h * 24 * NN;
  __hip_bfloat16* Arow = A + ((size_t)i * HH + h) * NN;

  float4 av[4];
#pragma unroll
  for (int t = 0; t < 4; t++) {
    const int j = t * 256 + lane * 4;
    float4 d = {0, 0, 0, 0};
#pragma unroll
    for (int c = 0; c < 16; c++) {
      const float qc = (c < 4 ? (&q0.x)[c] : c < 8 ? (&q1.x)[c - 4]
                       : c < 12 ? (&q2.x)[c - 8] : (&q3.x)[c - 12]);
      float4 kv = *reinterpret_cast<const float4*>(&kch[(size_t)c * NN + j]);
      d.x += qc * kv.x; d.y += qc * kv.y; d.z += qc * kv.z; d.w += qc * kv.w;
    }
    float4 cr = {0, 0, 0, 0};
#pragma unroll
    for (int dd = 0; dd < 12; dd++) {
      const float pc = (dd < 4 ? (&p0.x)[dd] : dd < 8 ? (&p1.x)[dd - 4]
                        : (&p2.x)[dd - 8]);
      float4 kv = *reinterpret_cast<const float4*>(&kpch[(size_t)dd * NN + j]);
      cr.x += pc * kv.x; cr.y += pc * kv.y; cr.z += pc * kv.z; cr.w += pc * kv.w;
    }
    float4 kn4 = *reinterpret_cast<const float4*>(&knch[j]);
    ushort4 bu = *reinterpret_cast<const ushort4*>(&Arow[j]);
    float4 m4 = *reinterpret_cast<const float4*>(&mask[j]);
    av[t].x = SC_QK * d.x + SC_B * (bf2f(bu.x) + bbv)
              - 0.5f * hwv * (qnv + kn4.x - 2.f * cr.x) + INF_ * (mi * m4.x - 1.f);
    av[t].y = SC_QK * d.y + SC_B * (bf2f(bu.y) + bbv)
              - 0.5f * hwv * (qnv + kn4.y - 2.f * cr.y) + INF_ * (mi * m4.y - 1.f);
    av[t].z = SC_QK * d.z + SC_B * (bf2f(bu.z) + bbv)
              - 0.5f * hwv * (qnv + kn4.z - 2.f * cr.z) + INF_ * (mi * m4.z - 1.f);
    av[t].w = SC_QK * d.w + SC_B * (bf2f(bu.w) + bbv)
              - 0.5f * hwv * (qnv + kn4.w - 2.f * cr.w) + INF_ * (mi * m4.w - 1.f);
  }

  float m = av[0].x;
#pragma unroll
  for (int t = 0; t < 4; t++) {
    m = fmaxf(m, av[t].x); m = fmaxf(m, av[t].y);
    m = fmaxf(m, av[t].z); m = fmaxf(m, av[t].w);
  }
  for (int off = 32; off; off >>= 1) m = fmaxf(m, __shfl_xor(m, off));
  float ssum = 0.f;
#pragma unroll
  for (int t = 0; t < 4; t++) {
    av[t].x = __expf(av[t].x - m); ssum += av[t].x;
    av[t].y = __expf(av[t].y - m); ssum += av[t].y;
    av[t].z = __expf(av[t].z - m); ssum += av[t].z;
    av[t].w = __expf(av[t].w - m); ssum += av[t].w;
  }
  for (int off = 32; off; off >>= 1) ssum += __shfl_xor(ssum, off);
  const float inv = 1.f / ssum;
#pragma unroll
  for (int t = 0; t < 4; t++) {
    const int j = t * 256 + lane * 4;
    av[t].x *= inv; av[t].y *= inv; av[t].z *= inv; av[t].w *= inv;
    ushort4 st;
    st.x = f2bf(av[t].x); st.y = f2bf(av[t].y);
    st.z = f2bf(av[t].z); st.w = f2bf(av[t].w);
    *reinterpret_cast<ushort4*>(&Arow[j]) = st;
  }

  float oacc[16], wacc[24];
#pragma unroll
  for (int c = 0; c < 16; c++) oacc[c] = 0.f;
#pragma unroll
  for (int d = 0; d < 24; d++) wacc[d] = 0.f;
#pragma unroll
  for (int t = 0; t < 4; t++) {
    const int j = t * 256 + lane * 4;
    const float4 a4 = av[t];
#pragma unroll
    for (int c = 0; c < 16; c++) {
      float4 vv = *reinterpret_cast<const float4*>(&vch[(size_t)c * NN + j]);
      oacc[c] += dot4(a4, vv);
    }
#pragma unroll
    for (int d = 0; d < 24; d++) {
      float4 wv = *reinterpret_cast<const float4*>(&vpch[(size_t)d * NN + j]);
      wacc[d] += dot4(a4, wv);
    }
  }
  for (int off = 32; off; off >>= 1) {
#pragma unroll
    for (int c = 0; c < 16; c++) oacc[c] += __shfl_xor(oacc[c], off);
#pragma unroll
    for (int d = 0; d < 24; d++) wacc[d] += __shfl_xor(wacc[d], off);
  }
  if (lane == 0) {
    float* cr = cat + (size_t)i * DCAT + h * 16;
#pragma unroll
    for (int c = 0; c < 16; c++) cr[c] = oacc[c];
    float* ob = optb + ((size_t)i * HH + h) * 24;
#pragma unroll
    for (int d = 0; d < 24; d++) ob[d] = wacc[d];
  }
}

// ---------------------------------------------------------------------------
// opair_pass v4: split-j partial o_pair. grid (4, 1024): block (sp, i) owns
// 256 rows. A staged once (12 KB); z read directly from global (coalesced).
// Writes partial[(i*4+sp)*1536 + h*128 + c].
// ---------------------------------------------------------------------------
__global__ __launch_bounds__(256) void opair_pass(
    const float* __restrict__ z, const __hip_bfloat16* __restrict__ A,
    float* __restrict__ partial)
{
  __shared__ float A_ls[256 * HH];  // 12 KB, [jloc][h]
  __shared__ float red[HH * CZ];    // 6 KB
  const int sp = blockIdx.x, i = blockIdx.y;
  const int jb = sp * 256;
  const int tid = threadIdx.x;
  const int c4 = (tid & 31) * 4, jsub = tid >> 5;

  for (int e = tid; e < HH * 64; e += 256) {
    int h = e >> 6, j4 = (e & 63) * 4;
    ushort4 au = *reinterpret_cast<const ushort4*>(
        &A[((size_t)i * HH + h) * NN + jb + j4]);
    A_ls[(j4 + 0) * HH + h] = bf2f(au.x);
    A_ls[(j4 + 1) * HH + h] = bf2f(au.y);
    A_ls[(j4 + 2) * HH + h] = bf2f(au.z);
    A_ls[(j4 + 3) * HH + h] = bf2f(au.w);
  }
  for (int e = tid; e < HH * CZ; e += 256) red[e] = 0.f;
  __syncthreads();

  float4 acc[HH];
#pragma unroll
  for (int h = 0; h < HH; h++) acc[h] = make_float4(0.f, 0.f, 0.f, 0.f);

  const float* zrow = z + ((size_t)i * NN + jb + jsub * 32) * CZ + c4;
  const float* arow = &A_ls[jsub * 32 * HH];
  for (int j0 = 0; j0 < 32; j0 += 4) {
#pragma unroll
    for (int jj = 0; jj < 4; jj++) {
      const int j = j0 + jj;
      float4 zq = *reinterpret_cast<const float4*>(&zrow[(size_t)j * CZ]);
      float4 a0 = *reinterpret_cast<const float4*>(&arow[j * HH]);
      float4 a1 = *reinterpret_cast<const float4*>(&arow[j * HH + 4]);
      float4 a2 = *reinterpret_cast<const float4*>(&arow[j * HH + 8]);
      acc[0].x += a0.x * zq.x; acc[0].y += a0.x * zq.y;
      acc[0].z += a0.x * zq.z; acc[0].w += a0.x * zq.w;
      acc[1].x += a0.y * zq.x; acc[1].y += a0.y * zq.y;
      acc[1].z += a0.y * zq.z; acc[1].w += a0.y * zq.w;
      acc[2].x += a0.z * zq.x; acc[2].y += a0.z * zq.y;
      acc[2].z += a0.z * zq.z; acc[2].w += a0.z * zq.w;
      acc[3].x += a0.w * zq.x; acc[3].y += a0.w * zq.y;
      acc[3].z += a0.w * zq.z; acc[3].w += a0.w * zq.w;
      acc[4].x += a1.x * zq.x; acc[4].y += a1.x * zq.y;
      acc[4].z += a1.x * zq.z; acc[4].w += a1.x * zq.w;
      acc[5].x += a1.y * zq.x; acc[5].y += a1.y * zq.y;
      acc[5].z += a1.y * zq.z; acc[5].w += a1.y * zq.w;
      acc[6].x += a1.z * zq.x; acc[6].y += a1.z * zq.y;
      acc[6].z += a1.z * zq.z; acc[6].w += a1.z * zq.w;
      acc[7].x += a1.w * zq.x; acc[7].y += a1.w * zq.y;
      acc[7].z += a1.w * zq.z; acc[7].w += a1.w * zq.w;
      acc[8].x += a2.x * zq.x; acc[8].y += a2.x * zq.y;
      acc[8].z += a2.x * zq.z; acc[8].w += a2.x * zq.w;
      acc[9].x += a2.y * zq.x; acc[9].y += a2.y * zq.y;
      acc[9].z += a2.y * zq.z; acc[9].w += a2.y * zq.w;
      acc[10].x += a2.z * zq.x; acc[10].y += a2.z * zq.y;
      acc[10].z += a2.z * zq.z; acc[10].w += a2.z * zq.w;
      acc[11].x += a2.w * zq.x; acc[11].y += a2.w * zq.y;
      acc[11].z += a2.w * zq.z; acc[11].w += a2.w * zq.w;
    }
  }
  for (int s = 0; s < 8; s++) {
    __syncthreads();
    if (jsub == s) {
#pragma unroll
      for (int h = 0; h < HH; h++) {
        red[h * CZ + c4 + 0] += acc[h].x;
        red[h * CZ + c4 + 1] += acc[h].y;
        red[h * CZ + c4 + 2] += acc[h].z;
        red[h * CZ + c4 + 3] += acc[h].w;
      }
    }
  }
  __syncthreads();
  float* pp = partial + ((size_t)(i * 4 + sp)) * (HH * CZ);
  for (int e = tid; e < HH * CZ; e += 256) pp[e] = red[e];
}

// ---------------------------------------------------------------------------
// opair_reduce (+fused finish): sum 4 partials -> cat[576:2112];
// inverse-rotate o_pt + norms -> cat[192:576]. grid NN, block 256.
// ---------------------------------------------------------------------------
__global__ __launch_bounds__(256) void opair_reduce(
    const float* __restrict__ partial, const float* __restrict__ optb,
    const float* __restrict__ rot, const float* __restrict__ trans,
    float* __restrict__ cat)
{
  const int i = blockIdx.x, tid = threadIdx.x;
  __shared__ float R_s[9], T_s[3];
  if (tid < 9) R_s[tid] = rot[i * 9 + tid];
  if (tid < 3) T_s[tid] = trans[i * 3 + tid];
  __syncthreads();

  const float* pp = partial + ((size_t)i * 4) * (HH * CZ);
  for (int e = tid; e < HH * CZ; e += 256) {
    float v = pp[e] + pp[HH * CZ + e] + pp[2 * HH * CZ + e] + pp[3 * HH * CZ + e];
    cat[(size_t)i * DCAT + 576 + e] = v;
  }
  if (tid < 96) {
    int h = tid >> 3, p = tid & 7;
    const float* ob = optb + ((size_t)i * HH + h) * 24 + p * 3;
    float gx = ob[0] - T_s[0];
    float gy = ob[1] - T_s[1];
    float gz = ob[2] - T_s[2];
    float lx = R_s[0] * gx + R_s[3] * gy + R_s[6] * gz;
    float ly = R_s[1] * gx + R_s[4] * gy + R_s[7] * gz;
    float lz = R_s[2] * gx + R_s[5] * gy + R_s[8] * gz;
    float* catr = cat + (size_t)i * DCAT;
    catr[192 + 0 * 96 + h * 8 + p] = lx;
    catr[192 + 1 * 96 + h * 8 + p] = ly;
    catr[192 + 2 * 96 + h * 8 + p] = lz;
    catr[480 + h * 8 + p] = sqrtf(lx * lx + ly * ly + lz * lz + 1e-8f);
  }
}

// ---------------------------------------------------------------------------
// out_gemm: out = cat @ wout + bout  (1024 x 2112 x 384)
// ---------------------------------------------------------------------------
__global__ __launch_bounds__(256) void out_gemm(
    const float* __restrict__ cat, const float* __restrict__ wout,
    const float* __restrict__ bout, float* __restrict__ out)
{
  __shared__ float c_lds[4 * DCAT];
  const int n0 = blockIdx.x * 4;
  const int cq = blockIdx.y * 128 + (threadIdx.x & 63) * 2;
  const int rg = threadIdx.x >> 6;
  for (int idx = threadIdx.x; idx < 4 * DCAT; idx += 256) {
    int r = idx / DCAT, kk = idx - r * DCAT;
    c_lds[idx] = cat[(size_t)(n0 + r) * DCAT + kk];
  }
  __syncthreads();
  float a0 = 0.f, a1 = 0.f;
  const float* crow = &c_lds[rg * DCAT];
#pragma unroll 4
  for (int kk = 0; kk < DCAT; kk++) {
    float cv = crow[kk];
    float2 w2 = *reinterpret_cast<const float2*>(&wout[(size_t)kk * CS + cq]);
    a0 += cv * w2.x; a1 += cv * w2.y;
  }
  float* o = out + (size_t)(n0 + rg) * CS + cq;
  o[0] = a0 + bout[cq]; o[1] = a1 + bout[cq + 1];
}

// ---------------------------------------------------------------------------
extern "C" void kernel_launch(void* const* d_in, const int* in_sizes, int n_in,
                              void* d_out, int out_size, void* d_ws, size_t ws_size,
                              hipStream_t stream) {
  const float* s      = (const float*)d_in[0];
  const float* z      = (const float*)d_in[1];
  const float* rot    = (const float*)d_in[2];
  const float* trans  = (const float*)d_in[3];
  const float* mask   = (const float*)d_in[4];
  const float* wq     = (const float*)d_in[5];
  const float* bq     = (const float*)d_in[6];
  const float* wkv    = (const float*)d_in[7];
  const float* bkv    = (const float*)d_in[8];
  const float* wqp    = (const float*)d_in[9];
  const float* bqp    = (const float*)d_in[10];
  const float* wkvp   = (const float*)d_in[11];
  const float* bkvp   = (const float*)d_in[12];
  const float* wb     = (const float*)d_in[13];
  const float* bb     = (const float*)d_in[14];
  const float* head_w = (const float*)d_in[15];
  const float* wout   = (const float*)d_in[16];
  const float* bout   = (const float*)d_in[17];
  float* out = (float*)d_out;

  // workspace layout (floats; all bases 16-float aligned)
  float* ws = (float*)d_ws;
  float* proj_buf = ws;                                  // 1,179,648
  float* kc_buf   = proj_buf + (size_t)NN * PROJW;       // 196,608
  float* vc_buf   = kc_buf + (size_t)HH * 16 * NN;       // 196,608
  float* kpc_buf  = vc_buf + (size_t)HH * 16 * NN;       // 147,456
  float* vpc_buf  = kpc_buf + (size_t)HH * 12 * NN;      // 294,912
  float* knc_buf  = vpc_buf + (size_t)HH * 24 * NN;      // 12,288
  float* qpts_buf = knc_buf + (size_t)HH * NN;           // 147,456
  float* qn_buf   = qpts_buf + (size_t)NN * QPR;         // 12,288
  float* wbt_buf  = qn_buf + NN * HH;                    // 1,536
  float* hw_buf   = wbt_buf + HH * CZ;                   // 16
  float* optb_buf = hw_buf + 16;                         // 294,912
  float* cat_buf  = optb_buf + (size_t)NN * HH * 24;     // 2,162,688
  float* part_buf = cat_buf + (size_t)NN * DCAT;         // 6,291,456
  __hip_bfloat16* A_buf =
      (__hip_bfloat16*)(part_buf + (size_t)4 * NN * HH * CZ);  // 12,582,912 bf16

  prep<<<dim3(1), dim3(256), 0, stream>>>(wb, head_w, wbt_buf, hw_buf);
  proj_all<<<dim3(NN / 8, 9), dim3(256), 0, stream>>>(
      s, wq, bq, wkv, bkv, wqp, bqp, wkvp, bkvp, proj_buf);
  ipa_transform<<<dim3(NN), dim3(256), 0, stream>>>(
      proj_buf, rot, trans, kc_buf, vc_buf, qpts_buf, kpc_buf, vpc_buf,
      qn_buf, knc_buf);
  bias_pass<<<dim3(8, NN), dim3(256), 0, stream>>>(z, wbt_buf, A_buf);
  ipa_attn<<<dim3(NN / 4, HH), dim3(256), 0, stream>>>(
      kc_buf, kpc_buf, knc_buf, vc_buf, vpc_buf, proj_buf, qpts_buf,
      qn_buf, bb, hw_buf, mask, A_buf, cat_buf, optb_buf);
  opair_pass<<<dim3(4, NN), dim3(256), 0, stream>>>(z, A_buf, part_buf);
  opair_reduce<<<dim3(NN), dim3(256), 0, stream>>>(
      part_buf, optb_buf, rot, trans, cat_buf);
  out_gemm<<<dim3(NN / 4, 3), dim3(256), 0, stream>>>(
      cat_buf, wout, bout, out);
}